// Round 14
// baseline (166.186 us; speedup 1.0000x reference)
//
#include <hip/hip_runtime.h>
#include <hip/hip_bf16.h>
#include <stdint.h>

typedef unsigned short u16;
typedef __attribute__((ext_vector_type(4))) short short4v;
typedef __attribute__((ext_vector_type(8))) short short8;
typedef __attribute__((ext_vector_type(4))) float f32x4;

#define NB 2
#define NN 2048
#define ND 1024
#define NH 16
#define NR 32
#define NM (NB*NN)      // 4096 rows
#define NHR 512         // h*r
#define NQKV 1536       // 3*h*r

static __device__ __forceinline__ u16 f2bf(float f) {   // RNE
  union { float f; uint32_t u; } v; v.f = f;
  uint32_t r = v.u + 0x7fffu + ((v.u >> 16) & 1u);
  return (u16)(r >> 16);
}
static __device__ __forceinline__ u16 fastbf(float f) { // round-half-up (2 ops)
  union { float f; uint32_t u; } v; v.f = f;
  return (u16)((v.u + 0x8000u) >> 16);
}

typedef __attribute__((address_space(1))) unsigned int as1_u32;
typedef __attribute__((address_space(3))) unsigned int as3_u32;

// async global->LDS, 16B per lane (wave-uniform base + lane*16, m104/m108).
static __device__ __forceinline__ void async_copy16(void* lds, const void* g) {
  __builtin_amdgcn_global_load_lds((as1_u32*)(uintptr_t)g,
                                   (as3_u32*)(uint32_t)(uintptr_t)lds,
                                   16, 0, 0);
}

// Depth-2 pipeline ordering (r14). Per tile: partial arrival drain
// (vmcnt(N) leaves the NEXT tile's loads in flight -- hipBLASLt pattern,
// "never vmcnt(0)") then ONE __syncthreads. Anti-dep proof for staging
// t+2 into buffer (t+2)%3 == (t-1)%3 right after barrier(t): any wave past
// barrier(t) finished compute(t-1), and every ds_read of tile t-1 was
// register-retired before its consuming MFMA issued (compiler lgkm waits),
// so no live reads of that buffer exist. r8 proved the compiler emits NO
// implicit vmcnt(0) before s_barrier for global_load_lds -- partial drains
// stick (unlike m131's defeated attempts on __syncthreads-only code).
#define ARRIVE(cond_more_in_flight, N) do {                      \
    if (cond_more_in_flight)                                     \
      asm volatile("s_waitcnt vmcnt(" #N ")" ::: "memory");      \
    else                                                         \
      asm volatile("s_waitcnt vmcnt(0)" ::: "memory");           \
    __syncthreads();                                             \
  } while (0)

// ---------------------------------------------------------------------------
// K0: fused prep -- one launch, block-partitioned:
//   [0,2048):    cast x fp32->bf16 (8 els/thread)
//   [2048,2304): cast Wproj
//   [2304,2496): build_wct: WcT[col][i] = sum_k W_w[h*64+k][i]*U[k][rr],
//                col = w*512+head*32+rr, Q cols scaled 1/8. U staged in LDS.
// ---------------------------------------------------------------------------
__global__ __launch_bounds__(256, 2)
void prep(const float* __restrict__ x, const float* __restrict__ Wproj,
          const float* __restrict__ Wq, const float* __restrict__ Wk,
          const float* __restrict__ Wv, const float* __restrict__ U,
          u16* __restrict__ xb, u16* __restrict__ Wpb, u16* __restrict__ WcT) {
  __shared__ float sU[64 * 32];
  const int blk = blockIdx.x;
  const int tid = threadIdx.x;
  if (blk < 2304) {                       // vector casts
    const float* in = (blk < 2048) ? x : Wproj;
    u16* o = (blk < 2048) ? xb : Wpb;
    const int i = ((blk < 2048) ? blk : (blk - 2048)) * 256 + tid;
    const float4* p = (const float4*)in + (size_t)i * 2;
    float4 a = p[0], b2 = p[1];
    short8 v;
    v[0] = f2bf(a.x);  v[1] = f2bf(a.y);  v[2] = f2bf(a.z);  v[3] = f2bf(a.w);
    v[4] = f2bf(b2.x); v[5] = f2bf(b2.y); v[6] = f2bf(b2.z); v[7] = f2bf(b2.w);
    *((short8*)o + i) = v;
  } else {                                // build_wct
    #pragma unroll
    for (int t = 0; t < 2; ++t)
      ((float4*)sU)[t * 256 + tid] = ((const float4*)U)[t * 256 + tid];
    __syncthreads();
    const int local = blk - 2304;         // 0..191
    const int wh = local >> 2;            // 0..47 = w*16+head
    const int w = wh >> 4, head = wh & 15;
    const float* W = (w == 0) ? Wq : (w == 1 ? Wk : Wv);
    const int i = (local & 3) * 256 + tid;
    const float* Wcol = W + (size_t)head * 64 * ND + i;
    float acc[32];
    #pragma unroll
    for (int rr = 0; rr < 32; ++rr) acc[rr] = 0.f;
    for (int kk = 0; kk < 64; ++kk) {
      const float wv = Wcol[(size_t)kk * ND];
      const float4* u4 = (const float4*)&sU[kk * 32];
      #pragma unroll
      for (int r4 = 0; r4 < 8; ++r4) {
        float4 u = u4[r4];
        acc[r4 * 4 + 0] += wv * u.x;
        acc[r4 * 4 + 1] += wv * u.y;
        acc[r4 * 4 + 2] += wv * u.z;
        acc[r4 * 4 + 3] += wv * u.w;
      }
    }
    const float sc = (w == 0) ? 0.125f : 1.0f;
    const int colBase = w * 512 + head * 32;
    #pragma unroll
    for (int rr = 0; rr < 32; ++rr)
      WcT[(size_t)(colBase + rr) * ND + i] = f2bf(acc[rr] * sc);
  }
}

// ---------------------------------------------------------------------------
// MFMA GEMM, 64x128 tile (M x N), BK=64: C = A[M x K] * BT[N x K]^T.
// r14: 3-buffer depth-2 pipeline, ONE barrier/tile, vmcnt(6) partial drains
// (6 staging loads per tile per thread; tile t+1 stays in flight across the
// barrier). LDS 3x24 = 72 KB -> 2 blocks/CU; the 2-deep prefetch substitutes
// intra-block overlap for the lost 3rd co-resident block.
// 4 waves, each owns 64 rows x 32 cols (4x2 MFMA tiles). XOR-swizzled LDS.
// XCD-rectangle swizzle (gridDim.y % 8 == 0). EPI=0: fp32 store; EPI=1: QKV.
// ---------------------------------------------------------------------------
template<int EPI>
__global__ __launch_bounds__(256, 2)
void gemm_bt(const u16* __restrict__ A, int lda,
             const u16* __restrict__ BT, int ldb, int K,
             u16* __restrict__ o0, u16* __restrict__ o1, u16* __restrict__ o2,
             float* __restrict__ fo) {
  __shared__ __align__(16) u16 lA[3][64 * 64];
  __shared__ __align__(16) u16 lB[3][128 * 64];
  const int tid = threadIdx.x;
  const int lane = tid & 63, quad = lane >> 4, l16 = lane & 15;
  const int wave = tid >> 6;
  const int wn = wave * 32;
  // XCD-rectangle swizzle
  const int GX = gridDim.x;
  const int flat = blockIdx.y * GX + blockIdx.x;
  const int xcd = flat & 7, s = flat >> 3;
  const int per = gridDim.y >> 3;
  const int brow = xcd * per + s / GX, bcol = s % GX;
  const int rowBase = brow * 64, colBase = bcol * 128;

  f32x4 acc[4][2];
  #pragma unroll
  for (int i = 0; i < 4; ++i)
    #pragma unroll
    for (int j = 0; j < 2; ++j)
      acc[i][j] = (f32x4){0.f, 0.f, 0.f, 0.f};

  #define GSTAGE(t_, bf_) do {                                              \
    const int kt0 = (t_) * 64;                                              \
    _Pragma("unroll")                                                       \
    for (int it = 0; it < 6; ++it) {                                        \
      const int cid = it * 256 + tid;                                       \
      if (it < 2) {                                                         \
        const int row = cid >> 3, pc = cid & 7;                             \
        const int gc = pc ^ (row & 7);                                      \
        async_copy16(&lA[bf_][cid * 8],                                     \
                     &A[(size_t)(rowBase + row) * lda + kt0 + gc * 8]);     \
      } else {                                                              \
        const int c2 = cid - 512;                                           \
        const int row = c2 >> 3, pc = c2 & 7;                               \
        const int gc = pc ^ (row & 7);                                      \
        async_copy16(&lB[bf_][c2 * 8],                                      \
                     &BT[(size_t)(colBase + row) * ldb + kt0 + gc * 8]);    \
      }                                                                     \
    }                                                                       \
  } while (0)

  const int NT = K / 64;
  GSTAGE(0, 0);
  if (NT > 1) GSTAGE(1, 1);
  for (int t = 0; t < NT; ++t) {
    ARRIVE(t + 1 < NT, 6);              // tile t arrived; t+1 may stay in flight
    if (t + 2 < NT) GSTAGE(t + 2, (t + 2) % 3);
    const int buf = t % 3;
    #pragma unroll
    for (int ks = 0; ks < 64; ks += 32) {
      short8 fa[4], fb[2];
      #pragma unroll
      for (int t2 = 0; t2 < 4; ++t2) {
        const int ra = t2 * 16 + l16;
        const int pa = ((ks >> 3) + quad) ^ (ra & 7);
        fa[t2] = *(const short8*)&lA[buf][ra * 64 + pa * 8];
      }
      #pragma unroll
      for (int t2 = 0; t2 < 2; ++t2) {
        const int rb = wn + t2 * 16 + l16;
        const int pb = ((ks >> 3) + quad) ^ (rb & 7);
        fb[t2] = *(const short8*)&lB[buf][rb * 64 + pb * 8];
      }
      #pragma unroll
      for (int mt = 0; mt < 4; ++mt)
        #pragma unroll
        for (int nt = 0; nt < 2; ++nt)
          acc[mt][nt] = __builtin_amdgcn_mfma_f32_16x16x32_bf16(
              fa[mt], fb[nt], acc[mt][nt], 0, 0, 0);
    }
  }
  #undef GSTAGE

  #pragma unroll
  for (int mt = 0; mt < 4; ++mt) {
    const int gr0 = rowBase + mt * 16 + quad * 4;
    #pragma unroll
    for (int nt = 0; nt < 2; ++nt) {
      const int c = colBase + wn + nt * 16 + l16;
      #pragma unroll
      for (int j = 0; j < 4; ++j) {
        const float v = acc[mt][nt][j];
        const int row = gr0 + j;
        if (EPI == 0) {
          fo[(size_t)row * 1024 + c] = v;
        } else {
          const int b = row >> 11, n = row & (NN - 1);
          const int w = c >> 9, ch = c & 511, head = ch >> 5, rr = ch & 31;
          if (w == 0)
            o0[(size_t)(((b * NH + head) * NN + n)) * NR + rr] = f2bf(v);
          else if (w == 1)
            o1[(size_t)(((b * NH + head) * NN + n)) * NR + rr] = f2bf(v);
          else
            o2[(size_t)((b * NH + head) * NR + rr) * NN + n] = f2bf(v);
        }
      }
    }
  }
}

// ---------------------------------------------------------------------------
// K3: causal flash attention, LDS-staged, fixed-ref softmax. r14: 3-buffer
// depth-2 pipeline, ONE barrier/tile, vmcnt(2) partial drains (2 staging
// loads per tile per thread). LDS 3x8 = 24 KB -> still 6 blocks/CU.
// Grid x = bh, y = reversed qblk: flat&7 = bh&7 pins each (b,h)'s K/V to one
// XCD's L2 (r12-verified win). S^T = K.Q^T; P^T C-layout == B-operand of
// mfma_16x16x16 -> PV from registers. p=exp(s) unscaled (|s|<~6); masked
// s=-1e30 -> exp=0; only diagonal tile masks.
// ---------------------------------------------------------------------------
__global__ __launch_bounds__(256, 6)
void flash_attn(const u16* __restrict__ q, const u16* __restrict__ k,
                const u16* __restrict__ vt, u16* __restrict__ z) {
  __shared__ __align__(16) u16 lK[3][64 * 32];   // [key][r]
  __shared__ __align__(16) u16 lV[3][32 * 64];   // [r][key], chunk-swizzled
  const int bh = blockIdx.x;
  const int b = bh >> 4, head = bh & 15;
  const int tid = threadIdx.x;
  const int lane = tid & 63, quad = lane >> 4, l16 = lane & 15;
  const int wave = tid >> 6;
  const int qblk = gridDim.y - 1 - blockIdx.y;   // heavy blocks dispatch first
  const int qb0 = qblk * 64;
  const int qbase = qb0 + wave * 16;
  const int qq = qbase + l16;

  const u16* qp = q  + (size_t)bh * NN * NR;
  const u16* kp = k  + (size_t)bh * NN * NR;
  const u16* vp = vt + (size_t)bh * NR * NN;

  // B-frag of Q: B[n=q=l16][kdim=quad*8+j]
  const short8 bq = *(const short8*)&qp[(size_t)(qbase + l16) * NR + quad * 8];

  f32x4 Ot0 = (f32x4){0.f,0.f,0.f,0.f};   // O^T rows r=quad*4+j,    col q=l16
  f32x4 Ot1 = (f32x4){0.f,0.f,0.f,0.f};   // O^T rows r=16+quad*4+j
  float ls = 0.f;

  // staging thread roles (constant across tiles)
  const int krow = tid >> 2, kc = tid & 3;            // K: 4 chunks/row
  const int vrow = tid >> 3, vpc = tid & 7;           // V: 8 chunks/row
  const int vgc = vpc ^ (vrow & 7);                   // swizzle source chunk

  #define STAGE(kt_, buf_) do {                                            \
    const int m0_ = (kt_) * 64;                                            \
    async_copy16(&lK[buf_][tid * 8], &kp[(size_t)(m0_ + krow) * NR + kc * 8]); \
    async_copy16(&lV[buf_][tid * 8], &vp[(size_t)vrow * NN + m0_ + vgc * 8]);  \
  } while (0)

  STAGE(0, 0);
  if (qblk >= 1) STAGE(1, 1);
  for (int kt = 0; kt <= qblk; ++kt) {
    ARRIVE(kt + 1 <= qblk, 2);       // tile kt arrived; kt+1 may stay in flight
    if (kt + 2 <= qblk) STAGE(kt + 2, (kt + 2) % 3);
    const int buf = kt % 3;

    const int m0 = kt * 64;
    f32x4 s[4];
    const f32x4 zero = (f32x4){0.f,0.f,0.f,0.f};
    #pragma unroll
    for (int g = 0; g < 4; ++g) {
      const short8 ak = *(const short8*)&lK[buf][(16 * g + l16) * 32 + quad * 8];
      s[g] = __builtin_amdgcn_mfma_f32_16x16x32_bf16(ak, bq, zero, 0, 0, 0);
    }
    if (kt == qblk) {                // diagonal tile: causal mask
      #pragma unroll
      for (int g = 0; g < 4; ++g)
        #pragma unroll
        for (int j = 0; j < 4; ++j)
          if (m0 + 16 * g + quad * 4 + j > qq) s[g][j] = -1e30f;
    }
    #pragma unroll
    for (int g = 0; g < 4; ++g) {
      const float p0 = __expf(s[g][0]), p1 = __expf(s[g][1]);
      const float p2 = __expf(s[g][2]), p3 = __expf(s[g][3]);
      ls += (p0 + p1) + (p2 + p3);
      short4v bp;
      bp[0] = fastbf(p0); bp[1] = fastbf(p1); bp[2] = fastbf(p2); bp[3] = fastbf(p3);
      // V^T frags: row r (=l16 / 16+l16), logical chunk 2g+(quad>>1),
      // physical chunk ^= r&7, +4 elements for odd quads.
      const int c0 = 2 * g + (quad >> 1), off = (quad & 1) * 4;
      const short4v av0 = *(const short4v*)
          &lV[buf][l16 * 64 + ((c0 ^ (l16 & 7)) * 8) + off];
      const short4v av1 = *(const short4v*)
          &lV[buf][(16 + l16) * 64 + ((c0 ^ ((16 + l16) & 7)) * 8) + off];
      Ot0 = __builtin_amdgcn_mfma_f32_16x16x16bf16_1k(av0, bp, Ot0, 0, 0, 0);
      Ot1 = __builtin_amdgcn_mfma_f32_16x16x16bf16_1k(av1, bp, Ot1, 0, 0, 0);
    }
  }
  #undef STAGE

  // complete l over keys (quads hold disjoint key subsets)
  ls += __shfl_xor(ls, 16);
  ls += __shfl_xor(ls, 32);
  const float inv = 1.f / ls;

  short4v o0, o1;
  #pragma unroll
  for (int j = 0; j < 4; ++j) {
    o0[j] = f2bf(Ot0[j] * inv);
    o1[j] = f2bf(Ot1[j] * inv);
  }
  u16* zr = z + (size_t)(b * NN + qq) * NHR + head * NR;
  *(short4v*)&zr[quad * 4]      = o0;
  *(short4v*)&zr[16 + quad * 4] = o1;
}

// ---------------------------------------------------------------------------
extern "C" void kernel_launch(void* const* d_in, const int* in_sizes, int n_in,
                              void* d_out, int out_size, void* d_ws, size_t ws_size,
                              hipStream_t stream) {
  const float* x     = (const float*)d_in[0];
  // d_in[1] = mask: causal additive mask, handled analytically (unused)
  const float* Wq    = (const float*)d_in[2];
  const float* Wk    = (const float*)d_in[3];
  const float* Wv    = (const float*)d_in[4];
  const float* U     = (const float*)d_in[5];
  const float* Wproj = (const float*)d_in[6];
  // d_in[7] = rel_bias_tokens: alibi dist==0 on causal support (unused)
  float* out = (float*)d_out;

  // Workspace (24 MB), u16 units:
  //   [0,8MB)  xb (bf16 x) -- dead after gemm<1>; z (4MB) aliases it
  //   [8,9MB)  Wpb  [9,12MB) WcT  [12,24MB) q, kk, vt
  u16* ws  = (u16*)d_ws;
  u16* xb  = ws;
  u16* z   = ws;
  u16* Wpb = ws + (size_t)4 * 1024 * 1024;
  u16* WcT = Wpb + (size_t)512 * 1024;
  u16* q   = ws + (size_t)6 * 1024 * 1024;
  u16* kk  = q  + (size_t)NB * NH * NN * NR;
  u16* vt  = kk + (size_t)NB * NH * NN * NR;

  prep<<<2496, 256, 0, stream>>>(x, Wproj, Wq, Wk, Wv, U, xb, Wpb, WcT);
  gemm_bt<1><<<dim3(NQKV / 128, NM / 64), 256, 0, stream>>>(
      xb, ND, WcT, ND, ND, q, kk, vt, nullptr);
  flash_attn<<<dim3(NB * NH, NN / 64), 256, 0, stream>>>(q, kk, vt, z);
  gemm_bt<0><<<dim3(ND / 128, NM / 64), 256, 0, stream>>>(
      z, NHR, Wpb, NHR, NHR, nullptr, nullptr, nullptr, out);
}

// Round 15
// 164.604 us; speedup vs baseline: 1.0096x; 1.0096x over previous
//
#include <hip/hip_runtime.h>
#include <hip/hip_bf16.h>
#include <stdint.h>

typedef unsigned short u16;
typedef __attribute__((ext_vector_type(4))) short short4v;
typedef __attribute__((ext_vector_type(8))) short short8;
typedef __attribute__((ext_vector_type(4))) float f32x4;

#define NB 2
#define NN 2048
#define ND 1024
#define NH 16
#define NR 32
#define NM (NB*NN)      // 4096 rows
#define NHR 512         // h*r
#define NQKV 1536       // 3*h*r

static __device__ __forceinline__ u16 f2bf(float f) {   // RNE
  union { float f; uint32_t u; } v; v.f = f;
  uint32_t r = v.u + 0x7fffu + ((v.u >> 16) & 1u);
  return (u16)(r >> 16);
}
static __device__ __forceinline__ u16 fastbf(float f) { // round-half-up (2 ops)
  union { float f; uint32_t u; } v; v.f = f;
  return (u16)((v.u + 0x8000u) >> 16);
}

typedef __attribute__((address_space(1))) unsigned int as1_u32;
typedef __attribute__((address_space(3))) unsigned int as3_u32;

// async global->LDS, 16B per lane (wave-uniform base + lane*16, m104/m108).
static __device__ __forceinline__ void async_copy16(void* lds, const void* g) {
  __builtin_amdgcn_global_load_lds((as1_u32*)(uintptr_t)g,
                                   (as3_u32*)(uint32_t)(uintptr_t)lds,
                                   16, 0, 0);
}

// Single-barrier double-buffer ordering (r13-proven):
//   explicit "s_waitcnt vmcnt(0) lgkmcnt(0)" then __syncthreads().
//   arrival: each wave drains its own global_load_lds before arriving ->
//     after the barrier the whole tile is in LDS.
//   anti-dep: each wave drains its own ds_reads (lgkmcnt) before arriving ->
//     STAGE(t+1) issued after the barrier can never overwrite live reads.
#define SB_BARRIER() do {                                        \
    asm volatile("s_waitcnt vmcnt(0) lgkmcnt(0)" ::: "memory");  \
    __syncthreads();                                             \
  } while (0)

// ---------------------------------------------------------------------------
// K0: fused prep -- one launch, block-partitioned:
//   [0,2048):    cast x fp32->bf16 (8 els/thread)
//   [2048,2304): cast Wproj
//   [2304,2496): build_wct: WcT[col][i] = sum_k W_w[h*64+k][i]*U[k][rr],
//                col = w*512+head*32+rr, Q cols scaled 1/8. U staged in LDS.
// ---------------------------------------------------------------------------
__global__ __launch_bounds__(256, 2)
void prep(const float* __restrict__ x, const float* __restrict__ Wproj,
          const float* __restrict__ Wq, const float* __restrict__ Wk,
          const float* __restrict__ Wv, const float* __restrict__ U,
          u16* __restrict__ xb, u16* __restrict__ Wpb, u16* __restrict__ WcT) {
  __shared__ float sU[64 * 32];
  const int blk = blockIdx.x;
  const int tid = threadIdx.x;
  if (blk < 2304) {                       // vector casts
    const float* in = (blk < 2048) ? x : Wproj;
    u16* o = (blk < 2048) ? xb : Wpb;
    const int i = ((blk < 2048) ? blk : (blk - 2048)) * 256 + tid;
    const float4* p = (const float4*)in + (size_t)i * 2;
    float4 a = p[0], b2 = p[1];
    short8 v;
    v[0] = f2bf(a.x);  v[1] = f2bf(a.y);  v[2] = f2bf(a.z);  v[3] = f2bf(a.w);
    v[4] = f2bf(b2.x); v[5] = f2bf(b2.y); v[6] = f2bf(b2.z); v[7] = f2bf(b2.w);
    *((short8*)o + i) = v;
  } else {                                // build_wct
    #pragma unroll
    for (int t = 0; t < 2; ++t)
      ((float4*)sU)[t * 256 + tid] = ((const float4*)U)[t * 256 + tid];
    __syncthreads();
    const int local = blk - 2304;         // 0..191
    const int wh = local >> 2;            // 0..47 = w*16+head
    const int w = wh >> 4, head = wh & 15;
    const float* W = (w == 0) ? Wq : (w == 1 ? Wk : Wv);
    const int i = (local & 3) * 256 + tid;
    const float* Wcol = W + (size_t)head * 64 * ND + i;
    float acc[32];
    #pragma unroll
    for (int rr = 0; rr < 32; ++rr) acc[rr] = 0.f;
    for (int kk = 0; kk < 64; ++kk) {
      const float wv = Wcol[(size_t)kk * ND];
      const float4* u4 = (const float4*)&sU[kk * 32];
      #pragma unroll
      for (int r4 = 0; r4 < 8; ++r4) {
        float4 u = u4[r4];
        acc[r4 * 4 + 0] += wv * u.x;
        acc[r4 * 4 + 1] += wv * u.y;
        acc[r4 * 4 + 2] += wv * u.z;
        acc[r4 * 4 + 3] += wv * u.w;
      }
    }
    const float sc = (w == 0) ? 0.125f : 1.0f;
    const int colBase = w * 512 + head * 32;
    #pragma unroll
    for (int rr = 0; rr < 32; ++rr)
      WcT[(size_t)(colBase + rr) * ND + i] = f2bf(acc[rr] * sc);
  }
}

// ---------------------------------------------------------------------------
// MFMA GEMM, 64x64 tile, BK=64: C = A[M x K] * BT[N x K]^T.
// r15: tile shrunk again (r12's proven lever): gemm<1> -> 1536 blocks
// (5/CU LDS-capped), gemm<0> -> 1024 blocks (4/CU, was grid-starved at 2).
// Single-barrier dbuf K-loop (r13 SB proof), LDS 2x(8+8) = 32 KB.
// 4 waves, each owns 64 rows x 16 cols (4x1 MFMA tiles, acc = 16 VGPR).
// Staging: 1024 16B-chunks, 4/thread, wave-uniform A/B split. XOR-swizzled.
// XCD-rectangle swizzle (gridDim.y % 8 == 0). EPI=0: fp32 store; EPI=1: QKV.
// ---------------------------------------------------------------------------
template<int EPI>
__global__ __launch_bounds__(256, 5)
void gemm_bt(const u16* __restrict__ A, int lda,
             const u16* __restrict__ BT, int ldb, int K,
             u16* __restrict__ o0, u16* __restrict__ o1, u16* __restrict__ o2,
             float* __restrict__ fo) {
  __shared__ __align__(16) u16 lA[2][64 * 64];
  __shared__ __align__(16) u16 lB[2][64 * 64];
  const int tid = threadIdx.x;
  const int lane = tid & 63, quad = lane >> 4, l16 = lane & 15;
  const int wave = tid >> 6;
  const int wn = wave * 16;
  // XCD-rectangle swizzle
  const int GX = gridDim.x;
  const int flat = blockIdx.y * GX + blockIdx.x;
  const int xcd = flat & 7, s = flat >> 3;
  const int per = gridDim.y >> 3;
  const int brow = xcd * per + s / GX, bcol = s % GX;
  const int rowBase = brow * 64, colBase = bcol * 64;

  f32x4 acc[4];
  #pragma unroll
  for (int i = 0; i < 4; ++i)
    acc[i] = (f32x4){0.f, 0.f, 0.f, 0.f};

  #define GSTAGE(t_, bf_) do {                                              \
    const int kt0 = (t_) * 64;                                              \
    _Pragma("unroll")                                                       \
    for (int it = 0; it < 4; ++it) {                                        \
      const int cid = it * 256 + tid;                                       \
      if (it < 2) {                                                         \
        const int row = cid >> 3, pc = cid & 7;                             \
        const int gc = pc ^ (row & 7);                                      \
        async_copy16(&lA[bf_][cid * 8],                                     \
                     &A[(size_t)(rowBase + row) * lda + kt0 + gc * 8]);     \
      } else {                                                              \
        const int c2 = cid - 512;                                           \
        const int row = c2 >> 3, pc = c2 & 7;                               \
        const int gc = pc ^ (row & 7);                                      \
        async_copy16(&lB[bf_][c2 * 8],                                      \
                     &BT[(size_t)(colBase + row) * ldb + kt0 + gc * 8]);    \
      }                                                                     \
    }                                                                       \
  } while (0)

  const int NT = K / 64;
  GSTAGE(0, 0);
  int buf = 0;
  for (int t = 0; t < NT; ++t) {
    SB_BARRIER();                       // tile t arrived; prev reads retired
    if (t + 1 < NT) GSTAGE(t + 1, buf ^ 1);
    #pragma unroll
    for (int ks = 0; ks < 64; ks += 32) {
      short8 fa[4], fb;
      #pragma unroll
      for (int t2 = 0; t2 < 4; ++t2) {
        const int ra = t2 * 16 + l16;
        const int pa = ((ks >> 3) + quad) ^ (ra & 7);
        fa[t2] = *(const short8*)&lA[buf][ra * 64 + pa * 8];
      }
      {
        const int rb = wn + l16;
        const int pb = ((ks >> 3) + quad) ^ (rb & 7);
        fb = *(const short8*)&lB[buf][rb * 64 + pb * 8];
      }
      #pragma unroll
      for (int mt = 0; mt < 4; ++mt)
        acc[mt] = __builtin_amdgcn_mfma_f32_16x16x32_bf16(
            fa[mt], fb, acc[mt], 0, 0, 0);
    }
    buf ^= 1;
  }
  #undef GSTAGE

  #pragma unroll
  for (int mt = 0; mt < 4; ++mt) {
    const int gr0 = rowBase + mt * 16 + quad * 4;
    const int c = colBase + wn + l16;
    #pragma unroll
    for (int j = 0; j < 4; ++j) {
      const float v = acc[mt][j];
      const int row = gr0 + j;
      if (EPI == 0) {
        fo[(size_t)row * 1024 + c] = v;
      } else {
        const int b = row >> 11, n = row & (NN - 1);
        const int w = c >> 9, ch = c & 511, head = ch >> 5, rr = ch & 31;
        if (w == 0)
          o0[(size_t)(((b * NH + head) * NN + n)) * NR + rr] = f2bf(v);
        else if (w == 1)
          o1[(size_t)(((b * NH + head) * NN + n)) * NR + rr] = f2bf(v);
        else
          o2[(size_t)((b * NH + head) * NR + rr) * NN + n] = f2bf(v);
      }
    }
  }
}

// ---------------------------------------------------------------------------
// K3: causal flash attention, LDS-staged, fixed-ref softmax (r13-proven,
// byte-identical). Single barrier per tile (SB proof). Grid x = bh, y =
// reversed qblk: flat&7 = bh&7 pins each (b,h)'s K/V to one XCD's L2.
// S^T = K.Q^T (C row=key-in-16=quad*4+j, col=q=l16); P^T C-layout ==
// B-operand of mfma_16x16x16 -> PV from registers. p=exp(s) unscaled
// (|s|<~6); masked s=-1e30 -> exp=0; only diagonal tile masks.
// ---------------------------------------------------------------------------
__global__ __launch_bounds__(256, 6)
void flash_attn(const u16* __restrict__ q, const u16* __restrict__ k,
                const u16* __restrict__ vt, u16* __restrict__ z) {
  __shared__ __align__(16) u16 lK[2][64 * 32];   // [key][r]
  __shared__ __align__(16) u16 lV[2][32 * 64];   // [r][key], chunk-swizzled
  const int bh = blockIdx.x;
  const int b = bh >> 4, head = bh & 15;
  const int tid = threadIdx.x;
  const int lane = tid & 63, quad = lane >> 4, l16 = lane & 15;
  const int wave = tid >> 6;
  const int qblk = gridDim.y - 1 - blockIdx.y;   // heavy blocks dispatch first
  const int qb0 = qblk * 64;
  const int qbase = qb0 + wave * 16;
  const int qq = qbase + l16;

  const u16* qp = q  + (size_t)bh * NN * NR;
  const u16* kp = k  + (size_t)bh * NN * NR;
  const u16* vp = vt + (size_t)bh * NR * NN;

  // B-frag of Q: B[n=q=l16][kdim=quad*8+j]
  const short8 bq = *(const short8*)&qp[(size_t)(qbase + l16) * NR + quad * 8];

  f32x4 Ot0 = (f32x4){0.f,0.f,0.f,0.f};   // O^T rows r=quad*4+j,    col q=l16
  f32x4 Ot1 = (f32x4){0.f,0.f,0.f,0.f};   // O^T rows r=16+quad*4+j
  float ls = 0.f;

  // staging thread roles (constant across tiles)
  const int krow = tid >> 2, kc = tid & 3;            // K: 4 chunks/row
  const int vrow = tid >> 3, vpc = tid & 7;           // V: 8 chunks/row
  const int vgc = vpc ^ (vrow & 7);                   // swizzle source chunk

  #define STAGE(kt_, buf_) do {                                            \
    const int m0_ = (kt_) * 64;                                            \
    async_copy16(&lK[buf_][tid * 8], &kp[(size_t)(m0_ + krow) * NR + kc * 8]); \
    async_copy16(&lV[buf_][tid * 8], &vp[(size_t)vrow * NN + m0_ + vgc * 8]);  \
  } while (0)

  STAGE(0, 0);
  int buf = 0;
  for (int kt = 0; kt <= qblk; ++kt) {
    SB_BARRIER();                    // tile kt arrived; prev reads retired
    if (kt < qblk) STAGE(kt + 1, buf ^ 1);

    const int m0 = kt * 64;
    f32x4 s[4];
    const f32x4 zero = (f32x4){0.f,0.f,0.f,0.f};
    #pragma unroll
    for (int g = 0; g < 4; ++g) {
      const short8 ak = *(const short8*)&lK[buf][(16 * g + l16) * 32 + quad * 8];
      s[g] = __builtin_amdgcn_mfma_f32_16x16x32_bf16(ak, bq, zero, 0, 0, 0);
    }
    if (kt == qblk) {                // diagonal tile: causal mask
      #pragma unroll
      for (int g = 0; g < 4; ++g)
        #pragma unroll
        for (int j = 0; j < 4; ++j)
          if (m0 + 16 * g + quad * 4 + j > qq) s[g][j] = -1e30f;
    }
    #pragma unroll
    for (int g = 0; g < 4; ++g) {
      const float p0 = __expf(s[g][0]), p1 = __expf(s[g][1]);
      const float p2 = __expf(s[g][2]), p3 = __expf(s[g][3]);
      ls += (p0 + p1) + (p2 + p3);
      short4v bp;
      bp[0] = fastbf(p0); bp[1] = fastbf(p1); bp[2] = fastbf(p2); bp[3] = fastbf(p3);
      // V^T frags: row r (=l16 / 16+l16), logical chunk 2g+(quad>>1),
      // physical chunk ^= r&7, +4 elements for odd quads.
      const int c0 = 2 * g + (quad >> 1), off = (quad & 1) * 4;
      const short4v av0 = *(const short4v*)
          &lV[buf][l16 * 64 + ((c0 ^ (l16 & 7)) * 8) + off];
      const short4v av1 = *(const short4v*)
          &lV[buf][(16 + l16) * 64 + ((c0 ^ ((16 + l16) & 7)) * 8) + off];
      Ot0 = __builtin_amdgcn_mfma_f32_16x16x16bf16_1k(av0, bp, Ot0, 0, 0, 0);
      Ot1 = __builtin_amdgcn_mfma_f32_16x16x16bf16_1k(av1, bp, Ot1, 0, 0, 0);
    }
    buf ^= 1;
  }
  #undef STAGE

  // complete l over keys (quads hold disjoint key subsets)
  ls += __shfl_xor(ls, 16);
  ls += __shfl_xor(ls, 32);
  const float inv = 1.f / ls;

  short4v o0, o1;
  #pragma unroll
  for (int j = 0; j < 4; ++j) {
    o0[j] = f2bf(Ot0[j] * inv);
    o1[j] = f2bf(Ot1[j] * inv);
  }
  u16* zr = z + (size_t)(b * NN + qq) * NHR + head * NR;
  *(short4v*)&zr[quad * 4]      = o0;
  *(short4v*)&zr[16 + quad * 4] = o1;
}

// ---------------------------------------------------------------------------
extern "C" void kernel_launch(void* const* d_in, const int* in_sizes, int n_in,
                              void* d_out, int out_size, void* d_ws, size_t ws_size,
                              hipStream_t stream) {
  const float* x     = (const float*)d_in[0];
  // d_in[1] = mask: causal additive mask, handled analytically (unused)
  const float* Wq    = (const float*)d_in[2];
  const float* Wk    = (const float*)d_in[3];
  const float* Wv    = (const float*)d_in[4];
  const float* U     = (const float*)d_in[5];
  const float* Wproj = (const float*)d_in[6];
  // d_in[7] = rel_bias_tokens: alibi dist==0 on causal support (unused)
  float* out = (float*)d_out;

  // Workspace (24 MB), u16 units:
  //   [0,8MB)  xb (bf16 x) -- dead after gemm<1>; z (4MB) aliases it
  //   [8,9MB)  Wpb  [9,12MB) WcT  [12,24MB) q, kk, vt
  u16* ws  = (u16*)d_ws;
  u16* xb  = ws;
  u16* z   = ws;
  u16* Wpb = ws + (size_t)4 * 1024 * 1024;
  u16* WcT = Wpb + (size_t)512 * 1024;
  u16* q   = ws + (size_t)6 * 1024 * 1024;
  u16* kk  = q  + (size_t)NB * NH * NN * NR;
  u16* vt  = kk + (size_t)NB * NH * NN * NR;

  prep<<<2496, 256, 0, stream>>>(x, Wproj, Wq, Wk, Wv, U, xb, Wpb, WcT);
  gemm_bt<1><<<dim3(NQKV / 64, NM / 64), 256, 0, stream>>>(
      xb, ND, WcT, ND, ND, q, kk, vt, nullptr);
  flash_attn<<<dim3(NB * NH, NN / 64), 256, 0, stream>>>(q, kk, vt, z);
  gemm_bt<0><<<dim3(ND / 64, NM / 64), 256, 0, stream>>>(
      z, NHR, Wpb, NHR, NHR, nullptr, nullptr, nullptr, out);
}

// Round 16
// 162.012 us; speedup vs baseline: 1.0258x; 1.0160x over previous
//
#include <hip/hip_runtime.h>
#include <hip/hip_bf16.h>
#include <stdint.h>

typedef unsigned short u16;
typedef __attribute__((ext_vector_type(4))) short short4v;
typedef __attribute__((ext_vector_type(8))) short short8;
typedef __attribute__((ext_vector_type(4))) float f32x4;

#define NB 2
#define NN 2048
#define ND 1024
#define NH 16
#define NR 32
#define NM (NB*NN)      // 4096 rows
#define NHR 512         // h*r
#define NQKV 1536       // 3*h*r

static __device__ __forceinline__ u16 f2bf(float f) {   // RNE
  union { float f; uint32_t u; } v; v.f = f;
  uint32_t r = v.u + 0x7fffu + ((v.u >> 16) & 1u);
  return (u16)(r >> 16);
}
static __device__ __forceinline__ u16 fastbf(float f) { // round-half-up (2 ops)
  union { float f; uint32_t u; } v; v.f = f;
  return (u16)((v.u + 0x8000u) >> 16);
}

typedef __attribute__((address_space(1))) unsigned int as1_u32;
typedef __attribute__((address_space(3))) unsigned int as3_u32;

// async global->LDS, 16B per lane (wave-uniform base + lane*16, m104/m108).
static __device__ __forceinline__ void async_copy16(void* lds, const void* g) {
  __builtin_amdgcn_global_load_lds((as1_u32*)(uintptr_t)g,
                                   (as3_u32*)(uint32_t)(uintptr_t)lds,
                                   16, 0, 0);
}

// Single-barrier double-buffer ordering (r13-proven):
//   explicit "s_waitcnt vmcnt(0) lgkmcnt(0)" then __syncthreads().
//   arrival: each wave drains its own global_load_lds before arriving ->
//     after the barrier the whole tile is in LDS.
//   anti-dep: each wave drains its own ds_reads (lgkmcnt) before arriving ->
//     STAGE(t+1) issued after the barrier can never overwrite live reads.
#define SB_BARRIER() do {                                        \
    asm volatile("s_waitcnt vmcnt(0) lgkmcnt(0)" ::: "memory");  \
    __syncthreads();                                             \
  } while (0)

// ---------------------------------------------------------------------------
// K0: fused prep -- one launch, block-partitioned (r13-identical):
//   [0,2048):    cast x fp32->bf16 (8 els/thread)
//   [2048,2304): cast Wproj
//   [2304,2496): build_wct: WcT[col][i] = sum_k W_w[h*64+k][i]*U[k][rr],
//                col = w*512+head*32+rr, Q cols scaled 1/8. U staged in LDS.
// ---------------------------------------------------------------------------
__global__ __launch_bounds__(256, 2)
void prep(const float* __restrict__ x, const float* __restrict__ Wproj,
          const float* __restrict__ Wq, const float* __restrict__ Wk,
          const float* __restrict__ Wv, const float* __restrict__ U,
          u16* __restrict__ xb, u16* __restrict__ Wpb, u16* __restrict__ WcT) {
  __shared__ float sU[64 * 32];
  const int blk = blockIdx.x;
  const int tid = threadIdx.x;
  if (blk < 2304) {                       // vector casts
    const float* in = (blk < 2048) ? x : Wproj;
    u16* o = (blk < 2048) ? xb : Wpb;
    const int i = ((blk < 2048) ? blk : (blk - 2048)) * 256 + tid;
    const float4* p = (const float4*)in + (size_t)i * 2;
    float4 a = p[0], b2 = p[1];
    short8 v;
    v[0] = f2bf(a.x);  v[1] = f2bf(a.y);  v[2] = f2bf(a.z);  v[3] = f2bf(a.w);
    v[4] = f2bf(b2.x); v[5] = f2bf(b2.y); v[6] = f2bf(b2.z); v[7] = f2bf(b2.w);
    *((short8*)o + i) = v;
  } else {                                // build_wct
    #pragma unroll
    for (int t = 0; t < 2; ++t)
      ((float4*)sU)[t * 256 + tid] = ((const float4*)U)[t * 256 + tid];
    __syncthreads();
    const int local = blk - 2304;         // 0..191
    const int wh = local >> 2;            // 0..47 = w*16+head
    const int w = wh >> 4, head = wh & 15;
    const float* W = (w == 0) ? Wq : (w == 1 ? Wk : Wv);
    const int i = (local & 3) * 256 + tid;
    const float* Wcol = W + (size_t)head * 64 * ND + i;
    float acc[32];
    #pragma unroll
    for (int rr = 0; rr < 32; ++rr) acc[rr] = 0.f;
    for (int kk = 0; kk < 64; ++kk) {
      const float wv = Wcol[(size_t)kk * ND];
      const float4* u4 = (const float4*)&sU[kk * 32];
      #pragma unroll
      for (int r4 = 0; r4 < 8; ++r4) {
        float4 u = u4[r4];
        acc[r4 * 4 + 0] += wv * u.x;
        acc[r4 * 4 + 1] += wv * u.y;
        acc[r4 * 4 + 2] += wv * u.z;
        acc[r4 * 4 + 3] += wv * u.w;
      }
    }
    const float sc = (w == 0) ? 0.125f : 1.0f;
    const int colBase = w * 512 + head * 32;
    #pragma unroll
    for (int rr = 0; rr < 32; ++rr)
      WcT[(size_t)(colBase + rr) * ND + i] = f2bf(acc[rr] * sc);
  }
}

// ---------------------------------------------------------------------------
// MFMA GEMM, 64x128 tile (M x N), BK=64 (r13-identical: the measured optimum
// -- r14 depth-2 and r15 64x64 both regressed). Single-barrier dbuf K-loop,
// LDS 2x(8+16) = 48 KB -> 3 blocks/CU. 4 waves, each 64 rows x 32 cols.
// Staging: 1536 16B-chunks, 6/thread, wave-uniform A/B split. XOR-swizzled.
// XCD-rectangle swizzle (gridDim.y % 8 == 0). EPI=0: fp32 store; EPI=1: QKV.
// ---------------------------------------------------------------------------
template<int EPI>
__global__ __launch_bounds__(256, 3)
void gemm_bt(const u16* __restrict__ A, int lda,
             const u16* __restrict__ BT, int ldb, int K,
             u16* __restrict__ o0, u16* __restrict__ o1, u16* __restrict__ o2,
             float* __restrict__ fo) {
  __shared__ __align__(16) u16 lA[2][64 * 64];
  __shared__ __align__(16) u16 lB[2][128 * 64];
  const int tid = threadIdx.x;
  const int lane = tid & 63, quad = lane >> 4, l16 = lane & 15;
  const int wave = tid >> 6;
  const int wn = wave * 32;
  // XCD-rectangle swizzle
  const int GX = gridDim.x;
  const int flat = blockIdx.y * GX + blockIdx.x;
  const int xcd = flat & 7, s = flat >> 3;
  const int per = gridDim.y >> 3;
  const int brow = xcd * per + s / GX, bcol = s % GX;
  const int rowBase = brow * 64, colBase = bcol * 128;

  f32x4 acc[4][2];
  #pragma unroll
  for (int i = 0; i < 4; ++i)
    #pragma unroll
    for (int j = 0; j < 2; ++j)
      acc[i][j] = (f32x4){0.f, 0.f, 0.f, 0.f};

  #define GSTAGE(t_, bf_) do {                                              \
    const int kt0 = (t_) * 64;                                              \
    _Pragma("unroll")                                                       \
    for (int it = 0; it < 6; ++it) {                                        \
      const int cid = it * 256 + tid;                                       \
      if (it < 2) {                                                         \
        const int row = cid >> 3, pc = cid & 7;                             \
        const int gc = pc ^ (row & 7);                                      \
        async_copy16(&lA[bf_][cid * 8],                                     \
                     &A[(size_t)(rowBase + row) * lda + kt0 + gc * 8]);     \
      } else {                                                              \
        const int c2 = cid - 512;                                           \
        const int row = c2 >> 3, pc = c2 & 7;                               \
        const int gc = pc ^ (row & 7);                                      \
        async_copy16(&lB[bf_][c2 * 8],                                      \
                     &BT[(size_t)(colBase + row) * ldb + kt0 + gc * 8]);    \
      }                                                                     \
    }                                                                       \
  } while (0)

  const int NT = K / 64;
  GSTAGE(0, 0);
  int buf = 0;
  for (int t = 0; t < NT; ++t) {
    SB_BARRIER();                       // tile t arrived; prev reads retired
    if (t + 1 < NT) GSTAGE(t + 1, buf ^ 1);
    #pragma unroll
    for (int ks = 0; ks < 64; ks += 32) {
      short8 fa[4], fb[2];
      #pragma unroll
      for (int t2 = 0; t2 < 4; ++t2) {
        const int ra = t2 * 16 + l16;
        const int pa = ((ks >> 3) + quad) ^ (ra & 7);
        fa[t2] = *(const short8*)&lA[buf][ra * 64 + pa * 8];
      }
      #pragma unroll
      for (int t2 = 0; t2 < 2; ++t2) {
        const int rb = wn + t2 * 16 + l16;
        const int pb = ((ks >> 3) + quad) ^ (rb & 7);
        fb[t2] = *(const short8*)&lB[buf][rb * 64 + pb * 8];
      }
      #pragma unroll
      for (int mt = 0; mt < 4; ++mt)
        #pragma unroll
        for (int nt = 0; nt < 2; ++nt)
          acc[mt][nt] = __builtin_amdgcn_mfma_f32_16x16x32_bf16(
              fa[mt], fb[nt], acc[mt][nt], 0, 0, 0);
    }
    buf ^= 1;
  }
  #undef GSTAGE

  #pragma unroll
  for (int mt = 0; mt < 4; ++mt) {
    const int gr0 = rowBase + mt * 16 + quad * 4;
    #pragma unroll
    for (int nt = 0; nt < 2; ++nt) {
      const int c = colBase + wn + nt * 16 + l16;
      #pragma unroll
      for (int j = 0; j < 4; ++j) {
        const float v = acc[mt][nt][j];
        const int row = gr0 + j;
        if (EPI == 0) {
          fo[(size_t)row * 1024 + c] = v;
        } else {
          const int b = row >> 11, n = row & (NN - 1);
          const int w = c >> 9, ch = c & 511, head = ch >> 5, rr = ch & 31;
          if (w == 0)
            o0[(size_t)(((b * NH + head) * NN + n)) * NR + rr] = f2bf(v);
          else if (w == 1)
            o1[(size_t)(((b * NH + head) * NN + n)) * NR + rr] = f2bf(v);
          else
            o2[(size_t)((b * NH + head) * NR + rr) * NN + n] = f2bf(v);
        }
      }
    }
  }
}

// ---------------------------------------------------------------------------
// K3: causal flash attention, LDS-staged, fixed-ref softmax. r16: 128-KEY
// tiles -- halves the barrier/drain count vs r13 (avg 16.5 -> 8.7 arrivals/
// block), doubles compute per prefetch. LDS 2x(8K+8K) = 32 KB (allows 5/CU;
// grid 1024 = 4/CU unchanged -- no occupancy cost, the r10 trap avoided).
// Even qblk: second 64-key half of the diagonal tile is fully masked
// (exp->0, ~3% extra MFMA). Scores per-16-key group in per-g registers.
// Grid x = bh, y = reversed qblk: flat&7 = bh&7 pins each (b,h)'s K/V to
// one XCD's L2. Single barrier/tile (SB proof). S^T = K.Q^T; P^T C-layout
// == B-operand of mfma_16x16x16 -> PV from registers.
// ---------------------------------------------------------------------------
__global__ __launch_bounds__(256, 4)
void flash_attn(const u16* __restrict__ q, const u16* __restrict__ k,
                const u16* __restrict__ vt, u16* __restrict__ z) {
  __shared__ __align__(16) u16 lK[2][128 * 32];  // [key][r]
  __shared__ __align__(16) u16 lV[2][32 * 128];  // [r][key], chunk-swizzled
  const int bh = blockIdx.x;
  const int b = bh >> 4, head = bh & 15;
  const int tid = threadIdx.x;
  const int lane = tid & 63, quad = lane >> 4, l16 = lane & 15;
  const int wave = tid >> 6;
  const int qblk = gridDim.y - 1 - blockIdx.y;   // heavy blocks dispatch first
  const int qb0 = qblk * 64;
  const int qbase = qb0 + wave * 16;
  const int qq = qbase + l16;

  const u16* qp = q  + (size_t)bh * NN * NR;
  const u16* kp = k  + (size_t)bh * NN * NR;
  const u16* vp = vt + (size_t)bh * NR * NN;

  // B-frag of Q: B[n=q=l16][kdim=quad*8+j]
  const short8 bq = *(const short8*)&qp[(size_t)(qbase + l16) * NR + quad * 8];

  f32x4 Ot0 = (f32x4){0.f,0.f,0.f,0.f};   // O^T rows r=quad*4+j,    col q=l16
  f32x4 Ot1 = (f32x4){0.f,0.f,0.f,0.f};   // O^T rows r=16+quad*4+j
  float ls = 0.f;

  // staging: 128x32 K (512 chunks) + 32x128 V (512 chunks), 4 its of 256,
  // each lane-consecutive (async dest = wave base + lane*16).
  // K: cid -> row = cid>>2, chunk = cid&3 (no swizzle).
  // V: vi -> vrow = vi>>4, phys chunk = vi&15; source logical chunk
  //    = (phys&8) | ((phys&7) ^ (vrow&7))  (XOR swizzle within 8-chunk half).
  #define STAGE(kt_, buf_) do {                                               \
    const int m0_ = (kt_) * 128;                                              \
    _Pragma("unroll")                                                         \
    for (int it = 0; it < 2; ++it) {                                          \
      const int cid = it * 256 + tid;                                         \
      const int krow = cid >> 2, kc = cid & 3;                                \
      async_copy16(&lK[buf_][cid * 8],                                        \
                   &kp[(size_t)(m0_ + krow) * NR + kc * 8]);                  \
    }                                                                         \
    _Pragma("unroll")                                                         \
    for (int it = 0; it < 2; ++it) {                                          \
      const int vi = it * 256 + tid;                                          \
      const int vrow = vi >> 4, vpc = vi & 15;                                \
      const int vgc = (vpc & 8) | ((vpc & 7) ^ (vrow & 7));                   \
      async_copy16(&lV[buf_][vi * 8],                                         \
                   &vp[(size_t)vrow * NN + m0_ + vgc * 8]);                   \
    }                                                                         \
  } while (0)

  const int nt = (qblk >> 1) + 1;       // 128-key tiles covering keys <= qq
  STAGE(0, 0);
  int buf = 0;
  for (int kt = 0; kt < nt; ++kt) {
    SB_BARRIER();                       // tile kt arrived; prev reads retired
    if (kt + 1 < nt) STAGE(kt + 1, buf ^ 1);

    const int m0 = kt * 128;
    const bool last = (kt == nt - 1);
    const f32x4 zero = (f32x4){0.f,0.f,0.f,0.f};
    #pragma unroll
    for (int g = 0; g < 8; ++g) {
      const short8 ak = *(const short8*)&lK[buf][(16 * g + l16) * 32 + quad * 8];
      f32x4 s = __builtin_amdgcn_mfma_f32_16x16x32_bf16(ak, bq, zero, 0, 0, 0);
      if (last) {                       // diagonal tile: causal mask
        #pragma unroll
        for (int j = 0; j < 4; ++j)
          if (m0 + 16 * g + quad * 4 + j > qq) s[j] = -1e30f;
      }
      const float p0 = __expf(s[0]), p1 = __expf(s[1]);
      const float p2 = __expf(s[2]), p3 = __expf(s[3]);
      ls += (p0 + p1) + (p2 + p3);
      short4v bp;
      bp[0] = fastbf(p0); bp[1] = fastbf(p1); bp[2] = fastbf(p2); bp[3] = fastbf(p3);
      // V^T frags: row r (=l16 / 16+l16), logical chunk c0 = 2g+(quad>>1),
      // phys = (c0&8) | ((c0&7) ^ (r&7)); +4 elements for odd quads.
      const int c0 = 2 * g + (quad >> 1), off = (quad & 1) * 4;
      const int ph = (c0 & 8) | ((c0 & 7) ^ (l16 & 7));   // (16+l16)&7 == l16&7
      const short4v av0 = *(const short4v*)&lV[buf][l16 * 128 + ph * 8 + off];
      const short4v av1 = *(const short4v*)&lV[buf][(16 + l16) * 128 + ph * 8 + off];
      Ot0 = __builtin_amdgcn_mfma_f32_16x16x16bf16_1k(av0, bp, Ot0, 0, 0, 0);
      Ot1 = __builtin_amdgcn_mfma_f32_16x16x16bf16_1k(av1, bp, Ot1, 0, 0, 0);
    }
    buf ^= 1;
  }
  #undef STAGE

  // complete l over keys (quads hold disjoint key subsets)
  ls += __shfl_xor(ls, 16);
  ls += __shfl_xor(ls, 32);
  const float inv = 1.f / ls;

  short4v o0, o1;
  #pragma unroll
  for (int j = 0; j < 4; ++j) {
    o0[j] = f2bf(Ot0[j] * inv);
    o1[j] = f2bf(Ot1[j] * inv);
  }
  u16* zr = z + (size_t)(b * NN + qq) * NHR + head * NR;
  *(short4v*)&zr[quad * 4]      = o0;
  *(short4v*)&zr[16 + quad * 4] = o1;
}

// ---------------------------------------------------------------------------
extern "C" void kernel_launch(void* const* d_in, const int* in_sizes, int n_in,
                              void* d_out, int out_size, void* d_ws, size_t ws_size,
                              hipStream_t stream) {
  const float* x     = (const float*)d_in[0];
  // d_in[1] = mask: causal additive mask, handled analytically (unused)
  const float* Wq    = (const float*)d_in[2];
  const float* Wk    = (const float*)d_in[3];
  const float* Wv    = (const float*)d_in[4];
  const float* U     = (const float*)d_in[5];
  const float* Wproj = (const float*)d_in[6];
  // d_in[7] = rel_bias_tokens: alibi dist==0 on causal support (unused)
  float* out = (float*)d_out;

  // Workspace (24 MB), u16 units:
  //   [0,8MB)  xb (bf16 x) -- dead after gemm<1>; z (4MB) aliases it
  //   [8,9MB)  Wpb  [9,12MB) WcT  [12,24MB) q, kk, vt
  u16* ws  = (u16*)d_ws;
  u16* xb  = ws;
  u16* z   = ws;
  u16* Wpb = ws + (size_t)4 * 1024 * 1024;
  u16* WcT = Wpb + (size_t)512 * 1024;
  u16* q   = ws + (size_t)6 * 1024 * 1024;
  u16* kk  = q  + (size_t)NB * NH * NN * NR;
  u16* vt  = kk + (size_t)NB * NH * NN * NR;

  prep<<<2496, 256, 0, stream>>>(x, Wproj, Wq, Wk, Wv, U, xb, Wpb, WcT);
  gemm_bt<1><<<dim3(NQKV / 128, NM / 64), 256, 0, stream>>>(
      xb, ND, WcT, ND, ND, q, kk, vt, nullptr);
  flash_attn<<<dim3(NB * NH, NN / 64), 256, 0, stream>>>(q, kk, vt, z);
  gemm_bt<0><<<dim3(ND / 128, NM / 64), 256, 0, stream>>>(
      z, NHR, Wpb, NHR, NHR, nullptr, nullptr, nullptr, out);
}